// Round 3
// baseline (214.287 us; speedup 1.0000x reference)
//
#include <hip/hip_runtime.h>
#include <hip/hip_cooperative_groups.h>
#include <math.h>

namespace cg = cooperative_groups;

// Problem constants (fixed by reference setup_inputs)
constexpr int B   = 128;
constexpr int T   = 300;
constexpr int D   = 1024;   // video dim
constexpr int DA  = 128;    // audio dim
constexpr int TS  = T - 1;  // 299 similarities per batch
constexpr int K   = 32;
constexpr int KP1 = K + 1;

constexpr int SEG  = 10;                      // sims per wave-segment
constexpr int WPB  = (TS + SEG - 1) / SEG;    // 30 segments per batch
constexpr int NSEG = B * WPB;                 // 3840

#define EPS_D 1e-5

__device__ __forceinline__ void loadrow(const float* __restrict__ row, int lane, float r[16]) {
    const float4* f = (const float4*)row;
#pragma unroll
    for (int j = 0; j < 4; ++j) {
        float4 x = f[lane + 64 * j];
        r[4 * j + 0] = x.x; r[4 * j + 1] = x.y;
        r[4 * j + 2] = x.z; r[4 * j + 3] = x.w;
    }
}

// ---- phase bodies (shared by cooperative and fallback paths) ----

__device__ __forceinline__ void sims_body(const float* __restrict__ video,
                                          float* __restrict__ sims,
                                          int wid, int lane, int nWaves) {
    for (int segi = wid; segi < NSEG; segi += nWaves) {
        int b   = segi / WPB;
        int seg = segi % WPB;
        int s0  = seg * SEG;
        const float* vb = video + (size_t)b * T * D;

        float p[16];
        loadrow(vb + (size_t)s0 * D, lane, p);
        double pn0 = 0.0;
#pragma unroll
        for (int j = 0; j < 16; ++j) pn0 += (double)p[j] * (double)p[j];

        double cnA[SEG], dtA[SEG];
#pragma unroll
        for (int i = 0; i < SEG; ++i) {
            int s = s0 + i;
            int rowIdx = min(s + 1, TS);   // clamp tail loads
            float c[16];
            loadrow(vb + (size_t)rowIdx * D, lane, c);
            double cn = 0.0, dt = 0.0;
#pragma unroll
            for (int j = 0; j < 16; ++j) {
                cn += (double)c[j] * (double)c[j];
                dt += (double)c[j] * (double)p[j];
            }
            cnA[i] = cn; dtA[i] = dt;
#pragma unroll
            for (int j = 0; j < 16; ++j) p[j] = c[j];
        }
#pragma unroll
        for (int o = 32; o; o >>= 1) {
            pn0 += __shfl_xor(pn0, o);
#pragma unroll
            for (int i = 0; i < SEG; ++i) {
                cnA[i] += __shfl_xor(cnA[i], o);
                dtA[i] += __shfl_xor(dtA[i], o);
            }
        }
        if (lane == 0) {
            double nprev = sqrt(pn0) + EPS_D;
#pragma unroll
            for (int i = 0; i < SEG; ++i) {
                int s = s0 + i;
                double ncur = sqrt(cnA[i]) + EPS_D;
                if (s < TS) sims[b * TS + s] = (float)(fabs(dtA[i]) / (nprev * ncur));
                nprev = ncur;
            }
        }
    }
}

// LDS rank-select: rank(e) = #{j : S[j]<S[e] || (S[j]==S[e] && j<e)}.
// rank<K are exactly top_k(-sim)'s stable winners; output position = rank.
__device__ __forceinline__ void select_body(const float* __restrict__ sims,
                                            int* __restrict__ idxg,
                                            float* S, int b, int tid) {
    for (int e = tid; e < TS; e += 256) S[e] = sims[b * TS + e];
    __syncthreads();
    for (int e = tid; e < TS; e += 256) {
        float val = S[e];
        int rank = 0;
#pragma unroll 4
        for (int j = 0; j < TS; ++j) {
            float sj = S[j];
            rank += (sj < val) || (sj == val && j < e);
        }
        if (rank < K) idxg[b * KP1 + 1 + rank] = e + 1;
    }
    if (tid == 0) idxg[b * KP1] = 0;
}

__device__ __forceinline__ void gather_row(const float* __restrict__ video,
                                           const float* __restrict__ audio,
                                           float* __restrict__ out,
                                           int r, int t, int tid) {
    int b = r / KP1;
    const float4* vs = (const float4*)(video + ((size_t)b * T + t) * D);
    float4*       vd = (float4*)(out + (size_t)r * D);
    vd[tid] = vs[tid];
    if (tid < DA / 4) {
        const float4* as = (const float4*)(audio + ((size_t)b * T + t) * DA);
        float4*       ad = (float4*)(out + (size_t)B * KP1 * D + (size_t)r * DA);
        ad[tid] = as[tid];
    }
}

// ---- cooperative fused kernel ----
__global__ __launch_bounds__(256, 4) void fused_kernel(const float* __restrict__ video,
                                                       const float* __restrict__ audio,
                                                       float* __restrict__ sims,
                                                       int* __restrict__ idxg,
                                                       float* __restrict__ out) {
    cg::grid_group grid = cg::this_grid();
    __shared__ float S[TS];

    int tid  = threadIdx.x;
    int lane = tid & 63;
    int wid  = (blockIdx.x * 256 + tid) >> 6;
    int nWaves = gridDim.x * 4;

    sims_body(video, sims, wid, lane, nWaves);
    __threadfence();
    grid.sync();

    if (blockIdx.x < B) {
        select_body(sims, idxg, S, blockIdx.x, tid);
        __threadfence();
    }
    grid.sync();

    int nRows = B * KP1;
    for (int r = blockIdx.x; r < nRows; r += gridDim.x)
        gather_row(video, audio, out, r, idxg[r], tid);
}

// ---- fallback (non-cooperative) kernels ----
__global__ __launch_bounds__(256) void sims_kernel(const float* __restrict__ video,
                                                   float* __restrict__ sims) {
    int lane = threadIdx.x & 63;
    int wid  = (blockIdx.x * 256 + threadIdx.x) >> 6;
    sims_body(video, sims, wid, lane, NSEG);
}

__global__ __launch_bounds__(256) void select_kernel(const float* __restrict__ sims,
                                                     int* __restrict__ idxg) {
    __shared__ float S[TS];
    select_body(sims, idxg, S, blockIdx.x, threadIdx.x);
}

__global__ __launch_bounds__(256) void gather_kernel(const float* __restrict__ video,
                                                     const float* __restrict__ audio,
                                                     const int* __restrict__ idxg,
                                                     float* __restrict__ out) {
    int r = blockIdx.y * KP1 + blockIdx.x;
    gather_row(video, audio, out, r, idxg[r], threadIdx.x);
}

extern "C" void kernel_launch(void* const* d_in, const int* in_sizes, int n_in,
                              void* d_out, int out_size, void* d_ws, size_t ws_size,
                              hipStream_t stream) {
    const float* video = (const float*)d_in[0];
    const float* audio = (const float*)d_in[1];
    float* out  = (float*)d_out;
    float* sims = (float*)d_ws;
    int*   idx  = (int*)((char*)d_ws + (size_t)B * TS * sizeof(float));

    int maxBlocksPerCU = 0;
    hipError_t oe = hipOccupancyMaxActiveBlocksPerMultiprocessor(&maxBlocksPerCU,
                                                                 fused_kernel, 256, 0);
    int grid = 1024;
    if (oe == hipSuccess && maxBlocksPerCU > 0) {
        int cap = maxBlocksPerCU * 256;   // 256 CUs
        if (cap < grid) grid = cap;
    }
    if (grid < B) grid = B;               // phase 2 needs >= B blocks

    void* args[] = {(void*)&video, (void*)&audio, (void*)&sims, (void*)&idx, (void*)&out};
    hipError_t le = hipLaunchCooperativeKernel((void*)fused_kernel, dim3(grid), dim3(256),
                                               args, 0, stream);
    if (le != hipSuccess) {
        // fallback: 3 plain launches (same math, same outputs)
        int nBlocks = (NSEG * 64 + 255) / 256;  // 960
        sims_kernel<<<nBlocks, 256, 0, stream>>>(video, sims);
        select_kernel<<<B, 256, 0, stream>>>(sims, idx);
        gather_kernel<<<dim3(KP1, B), 256, 0, stream>>>(video, audio, idx, out);
    }
}

// Round 5
// 76.726 us; speedup vs baseline: 2.7929x; 2.7929x over previous
//
#include <hip/hip_runtime.h>
#include <math.h>

// Problem constants (fixed by reference setup_inputs)
constexpr int B   = 128;
constexpr int T   = 300;
constexpr int D   = 1024;   // video dim
constexpr int DA  = 128;    // audio dim
constexpr int TS  = T - 1;  // 299 similarities per batch
constexpr int K   = 32;
constexpr int KP1 = K + 1;

constexpr int SEG  = 10;                      // sims per wave-segment
constexpr int WPB  = (TS + SEG - 1) / SEG;    // 30 segments per batch
constexpr int NSEG = B * WPB;                 // 3840

#define EPS_D 1e-5

__device__ __forceinline__ void loadrow(const float* __restrict__ row, int lane, float r[16]) {
    const float4* f = (const float4*)row;
#pragma unroll
    for (int j = 0; j < 4; ++j) {
        float4 x = f[lane + 64 * j];
        r[4 * j + 0] = x.x; r[4 * j + 1] = x.y;
        r[4 * j + 2] = x.z; r[4 * j + 3] = x.w;
    }
}

// Kernel 1: adjacent-frame |cosine| similarities.
// One wave handles SEG consecutive sims. Load loop is pure VMEM+FMA (per-lane
// f64 partials, no cross-lane ops); all butterfly reductions batched at the end.
// f64 accumulation => ordering matches the f32 reference exactly (absmax 0.0
// in R0/R1/R2).
__global__ __launch_bounds__(256) void sims_kernel(const float* __restrict__ video,
                                                   float* __restrict__ sims) {
    int gid  = blockIdx.x * 256 + threadIdx.x;
    int wid  = gid >> 6;
    int lane = threadIdx.x & 63;
    if (wid >= NSEG) return;
    int b   = wid / WPB;
    int seg = wid % WPB;
    int s0  = seg * SEG;
    const float* vb = video + (size_t)b * T * D;

    float p[16];
    loadrow(vb + (size_t)s0 * D, lane, p);
    double pn0 = 0.0;
#pragma unroll
    for (int j = 0; j < 16; ++j) pn0 += (double)p[j] * (double)p[j];

    double cnA[SEG], dtA[SEG];
#pragma unroll
    for (int i = 0; i < SEG; ++i) {
        int s = s0 + i;
        int rowIdx = min(s + 1, TS);   // clamp tail loads
        float c[16];
        loadrow(vb + (size_t)rowIdx * D, lane, c);
        double cn = 0.0, dt = 0.0;
#pragma unroll
        for (int j = 0; j < 16; ++j) {
            cn += (double)c[j] * (double)c[j];
            dt += (double)c[j] * (double)p[j];
        }
        cnA[i] = cn; dtA[i] = dt;
#pragma unroll
        for (int j = 0; j < 16; ++j) p[j] = c[j];
    }

#pragma unroll
    for (int o = 32; o; o >>= 1) {
        pn0 += __shfl_xor(pn0, o);
#pragma unroll
        for (int i = 0; i < SEG; ++i) {
            cnA[i] += __shfl_xor(cnA[i], o);
            dtA[i] += __shfl_xor(dtA[i], o);
        }
    }

    if (lane == 0) {
        double nprev = sqrt(pn0) + EPS_D;
#pragma unroll
        for (int i = 0; i < SEG; ++i) {
            int s = s0 + i;
            double ncur = sqrt(cnA[i]) + EPS_D;
            if (s < TS) sims[b * TS + s] = (float)(fabs(dtA[i]) / (nprev * ncur));
            nprev = ncur;
        }
    }
}

// Kernel 2: fused rank-select + gather. One block per batch.
// rank(e) = #{j : S[j]<S[e] || (S[j]==S[e] && j<e)} — rank<K are exactly
// top_k(-sim)'s stable winners, output position = rank. idx stays in LDS;
// then the block gathers its 33 video+audio rows (video is L2/L3-warm from
// kernel 1).
__global__ __launch_bounds__(256) void selgather_kernel(const float* __restrict__ video,
                                                        const float* __restrict__ audio,
                                                        const float* __restrict__ sims,
                                                        float* __restrict__ out) {
    __shared__ float S[TS];
    __shared__ int   idxs[KP1];
    int b   = blockIdx.x;
    int tid = threadIdx.x;

    for (int e = tid; e < TS; e += 256) S[e] = sims[b * TS + e];
    if (tid == 0) idxs[0] = 0;
    __syncthreads();

    for (int e = tid; e < TS; e += 256) {
        float val = S[e];
        int rank = 0;
#pragma unroll 4
        for (int j = 0; j < TS; ++j) {
            float sj = S[j];
            rank += (sj < val) || (sj == val && j < e);
        }
        if (rank < K) idxs[rank + 1] = e + 1;
    }
    __syncthreads();

    float* outA = out + (size_t)B * KP1 * D;   // audio section
#pragma unroll 4
    for (int k = 0; k < KP1; ++k) {
        int t = idxs[k];
        const float4* vs = (const float4*)(video + ((size_t)b * T + t) * D);
        float4*       vd = (float4*)(out + ((size_t)b * KP1 + k) * D);
        vd[tid] = vs[tid];
        if (tid < DA / 4) {
            const float4* as = (const float4*)(audio + ((size_t)b * T + t) * DA);
            float4*       ad = (float4*)(outA + ((size_t)b * KP1 + k) * DA);
            ad[tid] = as[tid];
        }
    }
}

extern "C" void kernel_launch(void* const* d_in, const int* in_sizes, int n_in,
                              void* d_out, int out_size, void* d_ws, size_t ws_size,
                              hipStream_t stream) {
    const float* video = (const float*)d_in[0];
    const float* audio = (const float*)d_in[1];
    float* out  = (float*)d_out;
    float* sims = (float*)d_ws;

    int nBlocks = (NSEG * 64 + 255) / 256;   // 960
    sims_kernel<<<nBlocks, 256, 0, stream>>>(video, sims);
    selgather_kernel<<<B, 256, 0, stream>>>(video, audio, sims, out);
}